// Round 4
// baseline (373.747 us; speedup 1.0000x reference)
//
#include <hip/hip_runtime.h>

typedef __bf16 bf16_t;
typedef __bf16 bf16x4 __attribute__((ext_vector_type(4)));
typedef __bf16 bf16x8 __attribute__((ext_vector_type(8)));
typedef float f32x4 __attribute__((ext_vector_type(4)));

#define GLB(p) ((const __attribute__((address_space(1))) void*)(p))
#define LDS(p) ((__attribute__((address_space(3))) void*)(p))

// ---------------------------------------------------------------------------
// fp32 -> bf16 bulk convert (8 elems/thread, 16B stores)
// ---------------------------------------------------------------------------
__global__ void f32_to_bf16(const float* __restrict__ src, bf16_t* __restrict__ dst, int n8)
{
    const int i = blockIdx.x * 256 + threadIdx.x;
    if (i >= n8) return;
    const f32x4 a = *(const f32x4*)&src[(size_t)i * 8];
    const f32x4 b = *(const f32x4*)&src[(size_t)i * 8 + 4];
    bf16x8 h = {(bf16_t)a[0], (bf16_t)a[1], (bf16_t)a[2], (bf16_t)a[3],
                (bf16_t)b[0], (bf16_t)b[1], (bf16_t)b[2], (bf16_t)b[3]};
    *(bf16x8*)&dst[(size_t)i * 8] = h;
}

// ---------------------------------------------------------------------------
// 256x256 8-phase GEMM.  BM=BN=256, BK=64, 512 thr (8 waves 2Mx4N),
// per-wave C = 128x64.  LDS 128 KiB, XOR swizzle (conflict-free, verified r3).
// NEW (r4): fragment registers double-buffered across phases — afr alternates
// per phase, bfr per phase-pair — so phase N+1's ds_reads don't WAR-stall on
// phase N's MFMAs (theory: the ~550 cyc/phase gap vs the m201 template).
// Counted vmcnt(6): 3 half-tiles in flight.  h0=B_k0,h1=A_k0,h2=B_k1,h3=A_k1.
// MODE 0: scatter -> q/k (B,H,T,hd), vT (B,H,hd,T).  MODE 1: fp32 store.
// ---------------------------------------------------------------------------
#define LDB4(d, kk, S)                                                         \
    { _Pragma("unroll") for (int nt = 0; nt < 4; ++nt)                         \
        bfr[S][nt] = *(const bf16x8*)&smem[sBe + (d) * 32768 + (kk) * 8192 + nt * 512]; }

#define LDA4(d, kk, g, S)                                                      \
    { _Pragma("unroll") for (int i = 0; i < 4; ++i)                            \
        afr[S][i] = *(const bf16x8*)&smem[sAe + (d) * 32768 + (kk) * 8192 + ((g) * 4 + i) * 512]; }

#define MM4(g, SA, SB)                                                         \
    { _Pragma("unroll") for (int i = 0; i < 4; ++i)                            \
        _Pragma("unroll") for (int nt = 0; nt < 4; ++nt)                       \
            acc[(g) * 4 + i][nt] = __builtin_amdgcn_mfma_f32_16x16x32_bf16(    \
                afr[SA][i], bfr[SB][nt], acc[(g) * 4 + i][nt], 0, 0, 0); }

#define PHASE_TAIL(g, SA, SB)                                                  \
    __builtin_amdgcn_s_barrier();                                              \
    asm volatile("s_waitcnt lgkmcnt(0)" ::: "memory");                         \
    __builtin_amdgcn_s_setprio(1);                                             \
    MM4(g, SA, SB);                                                            \
    __builtin_amdgcn_s_setprio(0);                                             \
    __builtin_amdgcn_s_barrier();

template <int MODE>
__global__ __launch_bounds__(512, 2)
void gemm256(const bf16_t* __restrict__ A, const bf16_t* __restrict__ Bm, int K,
             bf16_t* __restrict__ o0, bf16_t* __restrict__ o1, bf16_t* __restrict__ o2,
             float* __restrict__ of)
{
    __shared__ __align__(16) bf16_t smem[65536];   // 128 KiB

    const int tid  = threadIdx.x;
    const int lane = tid & 63;
    const int w    = tid >> 6;
    const int wr   = w >> 2;       // 0..1  (M rows of waves)
    const int wc   = w & 3;        // 0..3  (N cols of waves)
    const int quad = lane >> 4;
    const int qcol = lane & 15;
    const int m0   = blockIdx.x * 256;
    const int n0   = blockIdx.y * 256;

    f32x4 acc[8][4];
#pragma unroll
    for (int i = 0; i < 8; ++i)
#pragma unroll
        for (int j = 0; j < 4; ++j)
            acc[i][j] = (f32x4){0.f, 0.f, 0.f, 0.f};

    // ---- staging: half-tile = 256 rows x 32 k-cols; global col-group
    // pre-swizzled: scg = (lane&3) ^ ((lane>>3)&3)  [= (row>>1)&3].
    const int srow = w * 16 + (lane >> 2);
    const int scg  = (lane & 3) ^ ((lane >> 3) & 3);
    const bf16_t* Ag = A  + (size_t)(m0 + srow) * K + scg * 8;
    const bf16_t* Bg = Bm + (size_t)(n0 + srow) * K + scg * 8;

    auto STAGE = [&](int d, int t, int hh) {
        const int isA = hh & 1;
        const int kh  = hh >> 1;
        const bf16_t* g = (isA ? Ag : Bg) + t * 64 + kh * 32;
        bf16_t* l = &smem[d * 32768 + kh * 8192 + (isA ? 0 : 16384) + w * 512];
        __builtin_amdgcn_global_load_lds(GLB(g), LDS(l), 16, 0, 0);
        __builtin_amdgcn_global_load_lds(GLB(g + (size_t)128 * K), LDS(l + 4096), 16, 0, 0);
    };

    // ---- read bases (element units): row*32 + slot*8, slot = quad^((row>>1)&3)
    const int rs8 = (quad ^ ((qcol >> 1) & 3)) * 8;
    const int sAe = (wr * 128 + qcol) * 32 + rs8;
    const int sBe = 16384 + (wc * 64 + qcol) * 32 + rs8;

    bf16x8 afr[2][4], bfr[2][4];

    const int NT  = K >> 6;    // K-tiles of 64
    const int NIT = NT >> 1;   // 2 tiles per iteration

    // ---- prologue: tile0 fully staged, tile1 h0-h2 in flight ----
    STAGE(0, 0, 0); STAGE(0, 0, 1); STAGE(0, 0, 2); STAGE(0, 0, 3);
    STAGE(1, 1, 0); STAGE(1, 1, 1); STAGE(1, 1, 2);
    asm volatile("s_waitcnt vmcnt(6)" ::: "memory");
    __builtin_amdgcn_s_barrier();

    for (int J = 0; J < NIT - 1; ++J) {
        const int t = 2 * J;
        // ph1
        LDB4(0, 0, 0); LDA4(0, 0, 0, 0); STAGE(1, t + 1, 3);
        PHASE_TAIL(0, 0, 0);
        // ph2
        LDA4(0, 0, 1, 1); STAGE(0, t + 2, 0);
        PHASE_TAIL(1, 1, 0);
        // ph3
        LDB4(0, 1, 1); LDA4(0, 1, 0, 0); STAGE(0, t + 2, 1);
        PHASE_TAIL(0, 0, 1);
        // ph4
        LDA4(0, 1, 1, 1); STAGE(0, t + 2, 2);
        asm volatile("s_waitcnt vmcnt(6)" ::: "memory");
        PHASE_TAIL(1, 1, 1);
        // ph5
        LDB4(1, 0, 0); LDA4(1, 0, 0, 0); STAGE(0, t + 2, 3);
        PHASE_TAIL(0, 0, 0);
        // ph6
        LDA4(1, 0, 1, 1); STAGE(1, t + 3, 0);
        PHASE_TAIL(1, 1, 0);
        // ph7
        LDB4(1, 1, 1); LDA4(1, 1, 0, 0); STAGE(1, t + 3, 1);
        PHASE_TAIL(0, 0, 1);
        // ph8
        LDA4(1, 1, 1, 1); STAGE(1, t + 3, 2);
        asm volatile("s_waitcnt vmcnt(6)" ::: "memory");
        PHASE_TAIL(1, 1, 1);
    }

    // ---- final iteration (tiles NT-2, NT-1): drain ----
    {
        const int t = NT - 2;
        LDB4(0, 0, 0); LDA4(0, 0, 0, 0); STAGE(1, t + 1, 3);
        PHASE_TAIL(0, 0, 0);
        LDA4(0, 0, 1, 1);
        PHASE_TAIL(1, 1, 0);
        LDB4(0, 1, 1); LDA4(0, 1, 0, 0);
        PHASE_TAIL(0, 0, 1);
        LDA4(0, 1, 1, 1);
        asm volatile("s_waitcnt vmcnt(0)" ::: "memory");
        PHASE_TAIL(1, 1, 1);
        LDB4(1, 0, 0); LDA4(1, 0, 0, 0);
        PHASE_TAIL(0, 0, 0);
        LDA4(1, 0, 1, 1);
        PHASE_TAIL(1, 1, 0);
        LDB4(1, 1, 1); LDA4(1, 1, 0, 0);
        PHASE_TAIL(0, 0, 1);
        LDA4(1, 1, 1, 1);
        __builtin_amdgcn_s_barrier();
        asm volatile("s_waitcnt lgkmcnt(0)" ::: "memory");
        __builtin_amdgcn_s_setprio(1);
        MM4(1, 1, 1);
        __builtin_amdgcn_s_setprio(0);
    }

    // ---- epilogue ----
#pragma unroll
    for (int mt = 0; mt < 8; ++mt) {
#pragma unroll
        for (int nt = 0; nt < 4; ++nt) {
#pragma unroll
            for (int r = 0; r < 4; ++r) {
                const int m = m0 + wr * 128 + mt * 16 + quad * 4 + r;
                const int f = n0 + wc * 64 + nt * 16 + qcol;
                const float val = acc[mt][nt][r];
                if (MODE == 0) {
                    const int b     = m >> 9;          // T = 512
                    const int t     = m & 511;
                    const int which = f >> 11;
                    const int h     = (f >> 7) & 15;
                    const int d     = f & 127;
                    if (which == 2) {
                        o2[((size_t)(((b << 4) + h) * 128 + d) << 9) + t] = (bf16_t)val;
                    } else {
                        bf16_t* dst = (which == 0) ? o0 : o1;
                        dst[(size_t)(((b << 4) + h) * 512 + t) * 128 + d] = (bf16_t)val;
                    }
                } else {
                    of[(size_t)m * 2048 + f] = val;
                }
            }
        }
    }
}

// ---------------------------------------------------------------------------
// RoPE (in-place on bf16 q and k; v untouched)
// ---------------------------------------------------------------------------
__global__ void rope_kernel(bf16_t* __restrict__ q, bf16_t* __restrict__ k)
{
    const int id  = blockIdx.x * 256 + threadIdx.x;
    const int arr = id >> 19;
    const int rem = id & ((1 << 19) - 1);
    const int bh  = rem >> 12;
    const int t   = (rem >> 3) & 511;
    const int d   = rem & 7;

    bf16_t* p = (arr ? k : q) + (size_t)(bh * 512 + t) * 128;
    const float x1 = (float)p[d];
    const float x2 = (float)p[d + 8];
    const float freq = __expf(-(float)d * 1.1512925464970229f);  // ln(10000)/8
    const float ang  = (float)t * freq;
    const float c = cosf(ang), s = sinf(ang);
    p[d]     = (bf16_t)(x1 * c - x2 * s);
    p[d + 8] = (bf16_t)(x2 * c + x1 * s);
}

// ---------------------------------------------------------------------------
// MFMA flash attention, BQ=256, BK=64. Block = 256 thr (4 waves) per
// (b, h, 256-query tile); grid 2x16x8 = 256 blocks (1/CU).  Wave w owns 64
// queries (4 x 16-query groups qg) — K/V staged once per 256 queries (2x less
// staging+barriers per unit work than BQ=128).  S^T = K·Q^T; shfl softmax;
// P via wave-private LDS; O += P·V with V^T staged from (B,H,hd,T).
// ---------------------------------------------------------------------------
#define KLD 136
#define VLD 72
#define PLD 72

__global__ __launch_bounds__(256)
void flash_attn(const bf16_t* __restrict__ q, const bf16_t* __restrict__ k,
                const bf16_t* __restrict__ vT, bf16_t* __restrict__ y)
{
    const int qtb = blockIdx.x;   // 0..1 (256-query tiles)
    const int h   = blockIdx.y;
    const int b   = blockIdx.z;
    const int tid  = threadIdx.x;
    const int lane = tid & 63;
    const int w    = tid >> 6;
    const int quad = lane >> 4;
    const int qcol = lane & 15;

    __shared__ __align__(16) bf16_t Ks[64 * KLD];      // keys x dims   (17.4 KB)
    __shared__ __align__(16) bf16_t VTs[128 * VLD];    // dims x keys   (18.4 KB)
    __shared__ __align__(16) bf16_t Ps[256 * PLD];     // queries x keys(36.9 KB)
    __shared__ __align__(16) float aS[4][4][16];
    __shared__ __align__(16) float lS[4][4][16];

    const bf16_t* qb  = q  + (size_t)((b * 16 + h) * 512) * 128;
    const bf16_t* kb  = k  + (size_t)((b * 16 + h) * 512) * 128;
    const bf16_t* vtb = vT + (size_t)((b * 16 + h) * 128) * 512;

    // Q fragments (B-operand): query = qtb*256 + w*64 + qg*16 + qcol
    bf16x8 qfrag[4][4];
#pragma unroll
    for (int qg = 0; qg < 4; ++qg) {
        const int qrow = qtb * 256 + w * 64 + qg * 16 + qcol;
#pragma unroll
        for (int kc = 0; kc < 4; ++kc)
            qfrag[qg][kc] = *(const bf16x8*)&qb[(size_t)qrow * 128 + kc * 32 + quad * 8];
    }

    f32x4 acc_o[4][8];
#pragma unroll
    for (int qg = 0; qg < 4; ++qg)
#pragma unroll
        for (int nt = 0; nt < 8; ++nt) acc_o[qg][nt] = (f32x4){0.f, 0.f, 0.f, 0.f};
    float m_run[4] = {-INFINITY, -INFINITY, -INFINITY, -INFINITY};
    float l_run[4] = {0.f, 0.f, 0.f, 0.f};
    const float scale = 0.08838834764831845f;   // 1/sqrt(128)

    const int kt_last = 4 * qtb + 3;
    for (int kt = 0; kt <= kt_last; ++kt) {
        __syncthreads();
        // stage K tile (64 keys x 128 dims)
#pragma unroll
        for (int p = 0; p < 4; ++p) {
            const int r = p * 16 + (tid >> 4), c = (tid & 15) * 8;
            *(uint4*)&Ks[r * KLD + c] = *(const uint4*)&kb[(size_t)(kt * 64 + r) * 128 + c];
        }
        // stage V^T tile (128 dims x 64 keys)
#pragma unroll
        for (int p = 0; p < 4; ++p) {
            const int r = p * 32 + (tid >> 3), c = (tid & 7) * 8;
            *(uint4*)&VTs[r * VLD + c] = *(const uint4*)&vtb[(size_t)r * 512 + kt * 64 + c];
        }
        __syncthreads();

        const bool need_mask = (kt >= 4 * qtb);

#pragma unroll
        for (int qg = 0; qg < 4; ++qg) {
            // S^T (M=64 keys, N=16 queries, K=128): 16 MFMA
            f32x4 sacc[4];
#pragma unroll
            for (int mt = 0; mt < 4; ++mt) sacc[mt] = (f32x4){0.f, 0.f, 0.f, 0.f};
#pragma unroll
            for (int mt = 0; mt < 4; ++mt)
#pragma unroll
                for (int kc = 0; kc < 4; ++kc) {
                    bf16x8 af = *(const bf16x8*)&Ks[(mt * 16 + qcol) * KLD + kc * 32 + quad * 8];
                    sacc[mt] = __builtin_amdgcn_mfma_f32_16x16x32_bf16(af, qfrag[qg][kc], sacc[mt], 0, 0, 0);
                }

            float s[16];
#pragma unroll
            for (int mt = 0; mt < 4; ++mt)
#pragma unroll
                for (int r = 0; r < 4; ++r)
                    s[mt * 4 + r] = sacc[mt][r] * scale;
            if (need_mask) {
                const int qglob = qtb * 256 + w * 64 + qg * 16 + qcol;
#pragma unroll
                for (int mt = 0; mt < 4; ++mt)
#pragma unroll
                    for (int r = 0; r < 4; ++r)
                        if (kt * 64 + mt * 16 + quad * 4 + r > qglob)
                            s[mt * 4 + r] = -1e30f;
            }

            float mx = s[0];
#pragma unroll
            for (int i = 1; i < 16; ++i) mx = fmaxf(mx, s[i]);
            mx = fmaxf(mx, __shfl_xor(mx, 16));
            mx = fmaxf(mx, __shfl_xor(mx, 32));
            const float m_new = fmaxf(m_run[qg], mx);
            const float alpha = __expf(m_run[qg] - m_new);   // first iter: exp(-inf)=0
            float p16[16];
            float sum = 0.f;
#pragma unroll
            for (int i = 0; i < 16; ++i) { p16[i] = __expf(s[i] - m_new); sum += p16[i]; }
            sum += __shfl_xor(sum, 16);
            sum += __shfl_xor(sum, 32);
            l_run[qg] = l_run[qg] * alpha + sum;
            m_run[qg] = m_new;
            if (quad == 0) aS[w][qg][qcol] = alpha;

            // P -> wave-private LDS rows [w*64 + qg*16, +16)
#pragma unroll
            for (int mt = 0; mt < 4; ++mt) {
                bf16x4 pb = {(bf16_t)p16[mt * 4 + 0], (bf16_t)p16[mt * 4 + 1],
                             (bf16_t)p16[mt * 4 + 2], (bf16_t)p16[mt * 4 + 3]};
                *(bf16x4*)&Ps[(w * 64 + qg * 16 + qcol) * PLD + mt * 16 + quad * 4] = pb;
            }

            // rescale O rows (query = quad*4 + r within qg) by alpha
            f32x4 alpha4 = *(const f32x4*)&aS[w][qg][quad * 4];
#pragma unroll
            for (int nt = 0; nt < 8; ++nt)
#pragma unroll
                for (int r = 0; r < 4; ++r)
                    acc_o[qg][nt][r] *= alpha4[r];

            // O += P·V (M=16 queries, N=128 dims, K=64 keys): 16 MFMA
#pragma unroll
            for (int kc2 = 0; kc2 < 2; ++kc2) {
                bf16x8 pf = *(const bf16x8*)&Ps[(w * 64 + qg * 16 + qcol) * PLD + kc2 * 32 + quad * 8];
#pragma unroll
                for (int nt = 0; nt < 8; ++nt) {
                    bf16x8 vf = *(const bf16x8*)&VTs[(nt * 16 + qcol) * VLD + kc2 * 32 + quad * 8];
                    acc_o[qg][nt] = __builtin_amdgcn_mfma_f32_16x16x32_bf16(pf, vf, acc_o[qg][nt], 0, 0, 0);
                }
            }
        }
    }

    // epilogue: y[(b, t, h*128 + d)] = O / l
    if (quad == 0) {
#pragma unroll
        for (int qg = 0; qg < 4; ++qg) lS[w][qg][qcol] = l_run[qg];
    }
#pragma unroll
    for (int qg = 0; qg < 4; ++qg) {
        f32x4 l4 = *(const f32x4*)&lS[w][qg][quad * 4];
#pragma unroll
        for (int nt = 0; nt < 8; ++nt)
#pragma unroll
            for (int r = 0; r < 4; ++r) {
                const int t  = qtb * 256 + w * 64 + qg * 16 + quad * 4 + r;
                const int cc = h * 128 + nt * 16 + qcol;
                y[(size_t)(b * 512 + t) * 2048 + cc] = (bf16_t)(acc_o[qg][nt][r] / l4[r]);
            }
    }
}

// ---------------------------------------------------------------------------
extern "C" void kernel_launch(void* const* d_in, const int* in_sizes, int n_in,
                              void* d_out, int out_size, void* d_ws, size_t ws_size,
                              hipStream_t stream)
{
    (void)in_sizes; (void)n_in; (void)out_size; (void)ws_size;

    const float* x    = (const float*)d_in[0];   // (8, 512, 2048) fp32
    const float* Wqkv = (const float*)d_in[1];   // (6144, 2048)  fp32
    const float* Wout = (const float*)d_in[2];   // (2048, 2048)  fp32
    float* out = (float*)d_out;                  // (8, 512, 2048) fp32

    const size_t SEG = (size_t)8 * 16 * 512 * 128;   // 8,388,608 elems (16 MB bf16)
    bf16_t* q      = (bf16_t*)d_ws;          // [0, 16 MB)
    bf16_t* k      = q + SEG;                // [16, 32)
    bf16_t* vT     = k + SEG;                // [32, 48)   (B,H,hd,T)
    bf16_t* xb     = vT + SEG;               // [48, 64)   bf16 x — dead after GEMM1
    bf16_t* y      = xb;                     //            y aliases xb
    bf16_t* Wqkvb  = xb + SEG;               // [64, 88)   bf16 Wqkv
    bf16_t* Woutb  = Wqkvb + (size_t)6144 * 2048;   // [88, 96)

    f32_to_bf16<<<(8388608 / 8) / 256, 256, 0, stream>>>(x, xb, 8388608 / 8);
    f32_to_bf16<<<(12582912 / 8) / 256, 256, 0, stream>>>(Wqkv, Wqkvb, 12582912 / 8);
    f32_to_bf16<<<(4194304 / 8) / 256, 256, 0, stream>>>(Wout, Woutb, 4194304 / 8);
    gemm256<0><<<dim3(4096 / 256, 6144 / 256), 512, 0, stream>>>(xb, Wqkvb, 2048, q, k, vT, nullptr);
    rope_kernel<<<(2 * 128 * 512 * 8) / 256, 256, 0, stream>>>(q, k);
    flash_attn<<<dim3(2, 16, 8), 256, 0, stream>>>(q, k, vT, y);
    gemm256<1><<<dim3(4096 / 256, 2048 / 256), 512, 0, stream>>>(y, Woutb, 2048, nullptr, nullptr, nullptr, out);
}

// Round 5
// 365.200 us; speedup vs baseline: 1.0234x; 1.0234x over previous
//
#include <hip/hip_runtime.h>

typedef __bf16 bf16_t;
typedef __bf16 bf16x4 __attribute__((ext_vector_type(4)));
typedef __bf16 bf16x8 __attribute__((ext_vector_type(8)));
typedef float f32x4 __attribute__((ext_vector_type(4)));

#define GLB(p) ((const __attribute__((address_space(1))) void*)(p))
#define LDS(p) ((__attribute__((address_space(3))) void*)(p))

// ---------------------------------------------------------------------------
// fp32 -> bf16 bulk convert (8 elems/thread, 16B stores)
// ---------------------------------------------------------------------------
__global__ void f32_to_bf16(const float* __restrict__ src, bf16_t* __restrict__ dst, int n8)
{
    const int i = blockIdx.x * 256 + threadIdx.x;
    if (i >= n8) return;
    const f32x4 a = *(const f32x4*)&src[(size_t)i * 8];
    const f32x4 b = *(const f32x4*)&src[(size_t)i * 8 + 4];
    bf16x8 h = {(bf16_t)a[0], (bf16_t)a[1], (bf16_t)a[2], (bf16_t)a[3],
                (bf16_t)b[0], (bf16_t)b[1], (bf16_t)b[2], (bf16_t)b[3]};
    *(bf16x8*)&dst[(size_t)i * 8] = h;
}

// ---------------------------------------------------------------------------
// 256x256 8-phase GEMM.  BM=BN=256, BK=64, 512 thr (8 waves 2Mx4N),
// per-wave C = 128x64.  LDS 128 KiB, XOR swizzle (conflict-free, verified r3).
// Fragment regs double-buffered (r4, neutral but kept).  Counted vmcnt(6).
// Status r4: 145 us, MfmaUtil 30%, conflicts 0 — banked; no further schedule
// hypotheses without new evidence (two nulls: reg-dbuf, WAR).
// MODE 0: scatter -> q/k (B,H,T,hd), vT (B,H,hd,T).  MODE 1: fp32 store.
// ---------------------------------------------------------------------------
#define LDB4(d, kk, S)                                                         \
    { _Pragma("unroll") for (int nt = 0; nt < 4; ++nt)                         \
        bfr[S][nt] = *(const bf16x8*)&smem[sBe + (d) * 32768 + (kk) * 8192 + nt * 512]; }

#define LDA4(d, kk, g, S)                                                      \
    { _Pragma("unroll") for (int i = 0; i < 4; ++i)                            \
        afr[S][i] = *(const bf16x8*)&smem[sAe + (d) * 32768 + (kk) * 8192 + ((g) * 4 + i) * 512]; }

#define MM4(g, SA, SB)                                                         \
    { _Pragma("unroll") for (int i = 0; i < 4; ++i)                            \
        _Pragma("unroll") for (int nt = 0; nt < 4; ++nt)                       \
            acc[(g) * 4 + i][nt] = __builtin_amdgcn_mfma_f32_16x16x32_bf16(    \
                afr[SA][i], bfr[SB][nt], acc[(g) * 4 + i][nt], 0, 0, 0); }

#define PHASE_TAIL(g, SA, SB)                                                  \
    __builtin_amdgcn_s_barrier();                                              \
    asm volatile("s_waitcnt lgkmcnt(0)" ::: "memory");                         \
    __builtin_amdgcn_s_setprio(1);                                             \
    MM4(g, SA, SB);                                                            \
    __builtin_amdgcn_s_setprio(0);                                             \
    __builtin_amdgcn_s_barrier();

template <int MODE>
__global__ __launch_bounds__(512, 2)
void gemm256(const bf16_t* __restrict__ A, const bf16_t* __restrict__ Bm, int K,
             bf16_t* __restrict__ o0, bf16_t* __restrict__ o1, bf16_t* __restrict__ o2,
             float* __restrict__ of)
{
    __shared__ __align__(16) bf16_t smem[65536];   // 128 KiB

    const int tid  = threadIdx.x;
    const int lane = tid & 63;
    const int w    = tid >> 6;
    const int wr   = w >> 2;       // 0..1  (M rows of waves)
    const int wc   = w & 3;        // 0..3  (N cols of waves)
    const int quad = lane >> 4;
    const int qcol = lane & 15;
    const int m0   = blockIdx.x * 256;
    const int n0   = blockIdx.y * 256;

    f32x4 acc[8][4];
#pragma unroll
    for (int i = 0; i < 8; ++i)
#pragma unroll
        for (int j = 0; j < 4; ++j)
            acc[i][j] = (f32x4){0.f, 0.f, 0.f, 0.f};

    // ---- staging: half-tile = 256 rows x 32 k-cols; global col-group
    // pre-swizzled: scg = (lane&3) ^ ((lane>>3)&3)  [= (row>>1)&3].
    const int srow = w * 16 + (lane >> 2);
    const int scg  = (lane & 3) ^ ((lane >> 3) & 3);
    const bf16_t* Ag = A  + (size_t)(m0 + srow) * K + scg * 8;
    const bf16_t* Bg = Bm + (size_t)(n0 + srow) * K + scg * 8;

    auto STAGE = [&](int d, int t, int hh) {
        const int isA = hh & 1;
        const int kh  = hh >> 1;
        const bf16_t* g = (isA ? Ag : Bg) + t * 64 + kh * 32;
        bf16_t* l = &smem[d * 32768 + kh * 8192 + (isA ? 0 : 16384) + w * 512];
        __builtin_amdgcn_global_load_lds(GLB(g), LDS(l), 16, 0, 0);
        __builtin_amdgcn_global_load_lds(GLB(g + (size_t)128 * K), LDS(l + 4096), 16, 0, 0);
    };

    // ---- read bases (element units): row*32 + slot*8, slot = quad^((row>>1)&3)
    const int rs8 = (quad ^ ((qcol >> 1) & 3)) * 8;
    const int sAe = (wr * 128 + qcol) * 32 + rs8;
    const int sBe = 16384 + (wc * 64 + qcol) * 32 + rs8;

    bf16x8 afr[2][4], bfr[2][4];

    const int NT  = K >> 6;    // K-tiles of 64
    const int NIT = NT >> 1;   // 2 tiles per iteration

    // ---- prologue: tile0 fully staged, tile1 h0-h2 in flight ----
    STAGE(0, 0, 0); STAGE(0, 0, 1); STAGE(0, 0, 2); STAGE(0, 0, 3);
    STAGE(1, 1, 0); STAGE(1, 1, 1); STAGE(1, 1, 2);
    asm volatile("s_waitcnt vmcnt(6)" ::: "memory");
    __builtin_amdgcn_s_barrier();

    for (int J = 0; J < NIT - 1; ++J) {
        const int t = 2 * J;
        // ph1
        LDB4(0, 0, 0); LDA4(0, 0, 0, 0); STAGE(1, t + 1, 3);
        PHASE_TAIL(0, 0, 0);
        // ph2
        LDA4(0, 0, 1, 1); STAGE(0, t + 2, 0);
        PHASE_TAIL(1, 1, 0);
        // ph3
        LDB4(0, 1, 1); LDA4(0, 1, 0, 0); STAGE(0, t + 2, 1);
        PHASE_TAIL(0, 0, 1);
        // ph4
        LDA4(0, 1, 1, 1); STAGE(0, t + 2, 2);
        asm volatile("s_waitcnt vmcnt(6)" ::: "memory");
        PHASE_TAIL(1, 1, 1);
        // ph5
        LDB4(1, 0, 0); LDA4(1, 0, 0, 0); STAGE(0, t + 2, 3);
        PHASE_TAIL(0, 0, 0);
        // ph6
        LDA4(1, 0, 1, 1); STAGE(1, t + 3, 0);
        PHASE_TAIL(1, 1, 0);
        // ph7
        LDB4(1, 1, 1); LDA4(1, 1, 0, 0); STAGE(1, t + 3, 1);
        PHASE_TAIL(0, 0, 1);
        // ph8
        LDA4(1, 1, 1, 1); STAGE(1, t + 3, 2);
        asm volatile("s_waitcnt vmcnt(6)" ::: "memory");
        PHASE_TAIL(1, 1, 1);
    }

    // ---- final iteration (tiles NT-2, NT-1): drain ----
    {
        const int t = NT - 2;
        LDB4(0, 0, 0); LDA4(0, 0, 0, 0); STAGE(1, t + 1, 3);
        PHASE_TAIL(0, 0, 0);
        LDA4(0, 0, 1, 1);
        PHASE_TAIL(1, 1, 0);
        LDB4(0, 1, 1); LDA4(0, 1, 0, 0);
        PHASE_TAIL(0, 0, 1);
        LDA4(0, 1, 1, 1);
        asm volatile("s_waitcnt vmcnt(0)" ::: "memory");
        PHASE_TAIL(1, 1, 1);
        LDB4(1, 0, 0); LDA4(1, 0, 0, 0);
        PHASE_TAIL(0, 0, 0);
        LDA4(1, 0, 1, 1);
        PHASE_TAIL(1, 1, 0);
        LDB4(1, 1, 1); LDA4(1, 1, 0, 0);
        PHASE_TAIL(0, 0, 1);
        LDA4(1, 1, 1, 1);
        __builtin_amdgcn_s_barrier();
        asm volatile("s_waitcnt lgkmcnt(0)" ::: "memory");
        __builtin_amdgcn_s_setprio(1);
        MM4(1, 1, 1);
        __builtin_amdgcn_s_setprio(0);
    }

    // ---- epilogue ----
#pragma unroll
    for (int mt = 0; mt < 8; ++mt) {
#pragma unroll
        for (int nt = 0; nt < 4; ++nt) {
#pragma unroll
            for (int r = 0; r < 4; ++r) {
                const int m = m0 + wr * 128 + mt * 16 + quad * 4 + r;
                const int f = n0 + wc * 64 + nt * 16 + qcol;
                const float val = acc[mt][nt][r];
                if (MODE == 0) {
                    const int b     = m >> 9;          // T = 512
                    const int t     = m & 511;
                    const int which = f >> 11;
                    const int h     = (f >> 7) & 15;
                    const int d     = f & 127;
                    if (which == 2) {
                        o2[((size_t)(((b << 4) + h) * 128 + d) << 9) + t] = (bf16_t)val;
                    } else {
                        bf16_t* dst = (which == 0) ? o0 : o1;
                        dst[(size_t)(((b << 4) + h) * 512 + t) * 128 + d] = (bf16_t)val;
                    }
                } else {
                    of[(size_t)m * 2048 + f] = val;
                }
            }
        }
    }
}

// ---------------------------------------------------------------------------
// RoPE (in-place on bf16 q and k; v untouched)
// ---------------------------------------------------------------------------
__global__ void rope_kernel(bf16_t* __restrict__ q, bf16_t* __restrict__ k)
{
    const int id  = blockIdx.x * 256 + threadIdx.x;
    const int arr = id >> 19;
    const int rem = id & ((1 << 19) - 1);
    const int bh  = rem >> 12;
    const int t   = (rem >> 3) & 511;
    const int d   = rem & 7;

    bf16_t* p = (arr ? k : q) + (size_t)(bh * 512 + t) * 128;
    const float x1 = (float)p[d];
    const float x2 = (float)p[d + 8];
    const float freq = __expf(-(float)d * 1.1512925464970229f);  // ln(10000)/8
    const float ang  = (float)t * freq;
    const float c = cosf(ang), s = sinf(ang);
    p[d]     = (bf16_t)(x1 * c - x2 * s);
    p[d + 8] = (bf16_t)(x2 * c + x1 * s);
}

// ---------------------------------------------------------------------------
// MFMA flash attention, BQ=256, BK=64.  Block = 512 thr (8 waves = 2/SIMD)
// per (b, h, 256-query tile); grid 2x16x8 = 256 blocks.  Wave w owns 32
// queries (2 x 16-query groups qg) — r3's proven per-wave shape, but with
// K/V staged once per 256 queries AND 2 waves/SIMD to hide the serial
// QK->softmax->P->PV chain (r4's 1 wave/SIMD exposed it: +10 us).
// NEW: per-wave skip of fully-masked K-tiles (kt*64 > wave max query):
// skipped tiles contribute exactly 0 to m/l/O, and no barriers live inside
// the skipped region.  S^T = K·Q^T; shfl softmax; P via wave-private LDS;
// O += P·V with V^T staged from (B,H,hd,T).
// ---------------------------------------------------------------------------
#define KLD 136
#define VLD 72
#define PLD 72

__global__ __launch_bounds__(512)
void flash_attn(const bf16_t* __restrict__ q, const bf16_t* __restrict__ k,
                const bf16_t* __restrict__ vT, bf16_t* __restrict__ y)
{
    const int qtb = blockIdx.x;   // 0..1 (256-query tiles)
    const int h   = blockIdx.y;
    const int b   = blockIdx.z;
    const int tid  = threadIdx.x;
    const int lane = tid & 63;
    const int w    = tid >> 6;    // 0..7
    const int quad = lane >> 4;
    const int qcol = lane & 15;

    __shared__ __align__(16) bf16_t Ks[64 * KLD];      // keys x dims   (17.4 KB)
    __shared__ __align__(16) bf16_t VTs[128 * VLD];    // dims x keys   (18.4 KB)
    __shared__ __align__(16) bf16_t Ps[256 * PLD];     // queries x keys(36.9 KB)
    __shared__ __align__(16) float aS[8][2][16];
    __shared__ __align__(16) float lS[8][2][16];

    const bf16_t* qb  = q  + (size_t)((b * 16 + h) * 512) * 128;
    const bf16_t* kb  = k  + (size_t)((b * 16 + h) * 512) * 128;
    const bf16_t* vtb = vT + (size_t)((b * 16 + h) * 128) * 512;

    // Q fragments (B-operand): query = qtb*256 + w*32 + qg*16 + qcol
    bf16x8 qfrag[2][4];
#pragma unroll
    for (int qg = 0; qg < 2; ++qg) {
        const int qrow = qtb * 256 + w * 32 + qg * 16 + qcol;
#pragma unroll
        for (int kc = 0; kc < 4; ++kc)
            qfrag[qg][kc] = *(const bf16x8*)&qb[(size_t)qrow * 128 + kc * 32 + quad * 8];
    }

    f32x4 acc_o[2][8];
#pragma unroll
    for (int qg = 0; qg < 2; ++qg)
#pragma unroll
        for (int nt = 0; nt < 8; ++nt) acc_o[qg][nt] = (f32x4){0.f, 0.f, 0.f, 0.f};
    float m_run[2] = {-INFINITY, -INFINITY};
    float l_run[2] = {0.f, 0.f};
    const float scale = 0.08838834764831845f;   // 1/sqrt(128)

    const int wq_min  = qtb * 256 + w * 32;     // wave's lowest query
    const int kt_last = 4 * qtb + 3;
    for (int kt = 0; kt <= kt_last; ++kt) {
        __syncthreads();
        // stage K tile (64 keys x 128 dims): 512 thr x 2 x 16B
#pragma unroll
        for (int p = 0; p < 2; ++p) {
            const int r = p * 32 + (tid >> 4), c = (tid & 15) * 8;
            *(uint4*)&Ks[r * KLD + c] = *(const uint4*)&kb[(size_t)(kt * 64 + r) * 128 + c];
        }
        // stage V^T tile (128 dims x 64 keys): 512 thr x 2 x 16B
#pragma unroll
        for (int p = 0; p < 2; ++p) {
            const int r = p * 64 + (tid >> 3), c = (tid & 7) * 8;
            *(uint4*)&VTs[r * VLD + c] = *(const uint4*)&vtb[(size_t)r * 512 + kt * 64 + c];
        }
        __syncthreads();

        // per-wave: skip fully-masked tiles (all keys > all of wave's queries)
        if (kt * 64 > wq_min + 31) continue;
        const bool need_mask = ((kt + 1) * 64 > wq_min);

#pragma unroll
        for (int qg = 0; qg < 2; ++qg) {
            // S^T (M=64 keys, N=16 queries, K=128): 16 MFMA
            f32x4 sacc[4];
#pragma unroll
            for (int mt = 0; mt < 4; ++mt) sacc[mt] = (f32x4){0.f, 0.f, 0.f, 0.f};
#pragma unroll
            for (int mt = 0; mt < 4; ++mt)
#pragma unroll
                for (int kc = 0; kc < 4; ++kc) {
                    bf16x8 af = *(const bf16x8*)&Ks[(mt * 16 + qcol) * KLD + kc * 32 + quad * 8];
                    sacc[mt] = __builtin_amdgcn_mfma_f32_16x16x32_bf16(af, qfrag[qg][kc], sacc[mt], 0, 0, 0);
                }

            float s[16];
#pragma unroll
            for (int mt = 0; mt < 4; ++mt)
#pragma unroll
                for (int r = 0; r < 4; ++r)
                    s[mt * 4 + r] = sacc[mt][r] * scale;
            if (need_mask) {
                const int qglob = qtb * 256 + w * 32 + qg * 16 + qcol;
#pragma unroll
                for (int mt = 0; mt < 4; ++mt)
#pragma unroll
                    for (int r = 0; r < 4; ++r)
                        if (kt * 64 + mt * 16 + quad * 4 + r > qglob)
                            s[mt * 4 + r] = -1e30f;
            }

            float mx = s[0];
#pragma unroll
            for (int i = 1; i < 16; ++i) mx = fmaxf(mx, s[i]);
            mx = fmaxf(mx, __shfl_xor(mx, 16));
            mx = fmaxf(mx, __shfl_xor(mx, 32));
            const float m_new = fmaxf(m_run[qg], mx);
            const float alpha = __expf(m_run[qg] - m_new);   // first iter: exp(-inf)=0
            float p16[16];
            float sum = 0.f;
#pragma unroll
            for (int i = 0; i < 16; ++i) { p16[i] = __expf(s[i] - m_new); sum += p16[i]; }
            sum += __shfl_xor(sum, 16);
            sum += __shfl_xor(sum, 32);
            l_run[qg] = l_run[qg] * alpha + sum;
            m_run[qg] = m_new;
            if (quad == 0) aS[w][qg][qcol] = alpha;

            // P -> wave-private LDS rows [w*32 + qg*16, +16)
#pragma unroll
            for (int mt = 0; mt < 4; ++mt) {
                bf16x4 pb = {(bf16_t)p16[mt * 4 + 0], (bf16_t)p16[mt * 4 + 1],
                             (bf16_t)p16[mt * 4 + 2], (bf16_t)p16[mt * 4 + 3]};
                *(bf16x4*)&Ps[(w * 32 + qg * 16 + qcol) * PLD + mt * 16 + quad * 4] = pb;
            }

            // rescale O rows (query = quad*4 + r within qg) by alpha
            f32x4 alpha4 = *(const f32x4*)&aS[w][qg][quad * 4];
#pragma unroll
            for (int nt = 0; nt < 8; ++nt)
#pragma unroll
                for (int r = 0; r < 4; ++r)
                    acc_o[qg][nt][r] *= alpha4[r];

            // O += P·V (M=16 queries, N=128 dims, K=64 keys): 16 MFMA
#pragma unroll
            for (int kc2 = 0; kc2 < 2; ++kc2) {
                bf16x8 pf = *(const bf16x8*)&Ps[(w * 32 + qg * 16 + qcol) * PLD + kc2 * 32 + quad * 8];
#pragma unroll
                for (int nt = 0; nt < 8; ++nt) {
                    bf16x8 vf = *(const bf16x8*)&VTs[(nt * 16 + qcol) * VLD + kc2 * 32 + quad * 8];
                    acc_o[qg][nt] = __builtin_amdgcn_mfma_f32_16x16x32_bf16(pf, vf, acc_o[qg][nt], 0, 0, 0);
                }
            }
        }
    }

    // epilogue: y[(b, t, h*128 + d)] = O / l
    if (quad == 0) { lS[w][0][qcol] = l_run[0]; lS[w][1][qcol] = l_run[1]; }
#pragma unroll
    for (int qg = 0; qg < 2; ++qg) {
        f32x4 l4 = *(const f32x4*)&lS[w][qg][quad * 4];
#pragma unroll
        for (int nt = 0; nt < 8; ++nt)
#pragma unroll
            for (int r = 0; r < 4; ++r) {
                const int t  = qtb * 256 + w * 32 + qg * 16 + quad * 4 + r;
                const int cc = h * 128 + nt * 16 + qcol;
                y[(size_t)(b * 512 + t) * 2048 + cc] = (bf16_t)(acc_o[qg][nt][r] / l4[r]);
            }
    }
}

// ---------------------------------------------------------------------------
extern "C" void kernel_launch(void* const* d_in, const int* in_sizes, int n_in,
                              void* d_out, int out_size, void* d_ws, size_t ws_size,
                              hipStream_t stream)
{
    (void)in_sizes; (void)n_in; (void)out_size; (void)ws_size;

    const float* x    = (const float*)d_in[0];   // (8, 512, 2048) fp32
    const float* Wqkv = (const float*)d_in[1];   // (6144, 2048)  fp32
    const float* Wout = (const float*)d_in[2];   // (2048, 2048)  fp32
    float* out = (float*)d_out;                  // (8, 512, 2048) fp32

    const size_t SEG = (size_t)8 * 16 * 512 * 128;   // 8,388,608 elems (16 MB bf16)
    bf16_t* q      = (bf16_t*)d_ws;          // [0, 16 MB)
    bf16_t* k      = q + SEG;                // [16, 32)
    bf16_t* vT     = k + SEG;                // [32, 48)   (B,H,hd,T)
    bf16_t* xb     = vT + SEG;               // [48, 64)   bf16 x — dead after GEMM1
    bf16_t* y      = xb;                     //            y aliases xb
    bf16_t* Wqkvb  = xb + SEG;               // [64, 88)   bf16 Wqkv
    bf16_t* Woutb  = Wqkvb + (size_t)6144 * 2048;   // [88, 96)

    f32_to_bf16<<<(8388608 / 8) / 256, 256, 0, stream>>>(x, xb, 8388608 / 8);
    f32_to_bf16<<<(12582912 / 8) / 256, 256, 0, stream>>>(Wqkv, Wqkvb, 12582912 / 8);
    f32_to_bf16<<<(4194304 / 8) / 256, 256, 0, stream>>>(Wout, Woutb, 4194304 / 8);
    gemm256<0><<<dim3(4096 / 256, 6144 / 256), 512, 0, stream>>>(xb, Wqkvb, 2048, q, k, vT, nullptr);
    rope_kernel<<<(2 * 128 * 512 * 8) / 256, 256, 0, stream>>>(q, k);
    flash_attn<<<dim3(2, 16, 8), 512, 0, stream>>>(q, k, vT, y);
    gemm256<1><<<dim3(4096 / 256, 2048 / 256), 512, 0, stream>>>(y, Woutb, 2048, nullptr, nullptr, nullptr, out);
}

// Round 6
// 360.599 us; speedup vs baseline: 1.0365x; 1.0128x over previous
//
#include <hip/hip_runtime.h>

typedef __bf16 bf16_t;
typedef __bf16 bf16x4 __attribute__((ext_vector_type(4)));
typedef __bf16 bf16x8 __attribute__((ext_vector_type(8)));
typedef float f32x4 __attribute__((ext_vector_type(4)));

#define GLB(p) ((const __attribute__((address_space(1))) void*)(p))
#define LDS(p) ((__attribute__((address_space(3))) void*)(p))

// ---------------------------------------------------------------------------
// fp32 -> bf16 bulk convert (8 elems/thread, 16B stores)
// ---------------------------------------------------------------------------
__global__ void f32_to_bf16(const float* __restrict__ src, bf16_t* __restrict__ dst, int n8)
{
    const int i = blockIdx.x * 256 + threadIdx.x;
    if (i >= n8) return;
    const f32x4 a = *(const f32x4*)&src[(size_t)i * 8];
    const f32x4 b = *(const f32x4*)&src[(size_t)i * 8 + 4];
    bf16x8 h = {(bf16_t)a[0], (bf16_t)a[1], (bf16_t)a[2], (bf16_t)a[3],
                (bf16_t)b[0], (bf16_t)b[1], (bf16_t)b[2], (bf16_t)b[3]};
    *(bf16x8*)&dst[(size_t)i * 8] = h;
}

// ---------------------------------------------------------------------------
// 256x256 8-phase GEMM — used for GEMM1 only (M=4096, N=6144): 384 blocks,
// 146 us, MfmaUtil 29%, conflicts 0 (r3-r5 stable).  For GEMM2 (N=2048) this
// shape gives only 128 blocks = half-chip tail -> use gemm_bt below instead.
// MODE 0: scatter -> q/k (B,H,T,hd), vT (B,H,hd,T).
// ---------------------------------------------------------------------------
#define LDB4(d, kk, S)                                                         \
    { _Pragma("unroll") for (int nt = 0; nt < 4; ++nt)                         \
        bfr[S][nt] = *(const bf16x8*)&smem[sBe + (d) * 32768 + (kk) * 8192 + nt * 512]; }

#define LDA4(d, kk, g, S)                                                      \
    { _Pragma("unroll") for (int i = 0; i < 4; ++i)                            \
        afr[S][i] = *(const bf16x8*)&smem[sAe + (d) * 32768 + (kk) * 8192 + ((g) * 4 + i) * 512]; }

#define MM4(g, SA, SB)                                                         \
    { _Pragma("unroll") for (int i = 0; i < 4; ++i)                            \
        _Pragma("unroll") for (int nt = 0; nt < 4; ++nt)                       \
            acc[(g) * 4 + i][nt] = __builtin_amdgcn_mfma_f32_16x16x32_bf16(    \
                afr[SA][i], bfr[SB][nt], acc[(g) * 4 + i][nt], 0, 0, 0); }

#define PHASE_TAIL(g, SA, SB)                                                  \
    __builtin_amdgcn_s_barrier();                                              \
    asm volatile("s_waitcnt lgkmcnt(0)" ::: "memory");                         \
    __builtin_amdgcn_s_setprio(1);                                             \
    MM4(g, SA, SB);                                                            \
    __builtin_amdgcn_s_setprio(0);                                             \
    __builtin_amdgcn_s_barrier();

template <int MODE>
__global__ __launch_bounds__(512, 2)
void gemm256(const bf16_t* __restrict__ A, const bf16_t* __restrict__ Bm, int K,
             bf16_t* __restrict__ o0, bf16_t* __restrict__ o1, bf16_t* __restrict__ o2,
             float* __restrict__ of)
{
    __shared__ __align__(16) bf16_t smem[65536];   // 128 KiB

    const int tid  = threadIdx.x;
    const int lane = tid & 63;
    const int w    = tid >> 6;
    const int wr   = w >> 2;       // 0..1  (M rows of waves)
    const int wc   = w & 3;        // 0..3  (N cols of waves)
    const int quad = lane >> 4;
    const int qcol = lane & 15;
    const int m0   = blockIdx.x * 256;
    const int n0   = blockIdx.y * 256;

    f32x4 acc[8][4];
#pragma unroll
    for (int i = 0; i < 8; ++i)
#pragma unroll
        for (int j = 0; j < 4; ++j)
            acc[i][j] = (f32x4){0.f, 0.f, 0.f, 0.f};

    // ---- staging: half-tile = 256 rows x 32 k-cols; global col-group
    // pre-swizzled: scg = (lane&3) ^ ((lane>>3)&3)  [= (row>>1)&3].
    const int srow = w * 16 + (lane >> 2);
    const int scg  = (lane & 3) ^ ((lane >> 3) & 3);
    const bf16_t* Ag = A  + (size_t)(m0 + srow) * K + scg * 8;
    const bf16_t* Bg = Bm + (size_t)(n0 + srow) * K + scg * 8;

    auto STAGE = [&](int d, int t, int hh) {
        const int isA = hh & 1;
        const int kh  = hh >> 1;
        const bf16_t* g = (isA ? Ag : Bg) + t * 64 + kh * 32;
        bf16_t* l = &smem[d * 32768 + kh * 8192 + (isA ? 0 : 16384) + w * 512];
        __builtin_amdgcn_global_load_lds(GLB(g), LDS(l), 16, 0, 0);
        __builtin_amdgcn_global_load_lds(GLB(g + (size_t)128 * K), LDS(l + 4096), 16, 0, 0);
    };

    // ---- read bases (element units): row*32 + slot*8, slot = quad^((row>>1)&3)
    const int rs8 = (quad ^ ((qcol >> 1) & 3)) * 8;
    const int sAe = (wr * 128 + qcol) * 32 + rs8;
    const int sBe = 16384 + (wc * 64 + qcol) * 32 + rs8;

    bf16x8 afr[2][4], bfr[2][4];

    const int NT  = K >> 6;    // K-tiles of 64
    const int NIT = NT >> 1;   // 2 tiles per iteration

    // ---- prologue: tile0 fully staged, tile1 h0-h2 in flight ----
    STAGE(0, 0, 0); STAGE(0, 0, 1); STAGE(0, 0, 2); STAGE(0, 0, 3);
    STAGE(1, 1, 0); STAGE(1, 1, 1); STAGE(1, 1, 2);
    asm volatile("s_waitcnt vmcnt(6)" ::: "memory");
    __builtin_amdgcn_s_barrier();

    for (int J = 0; J < NIT - 1; ++J) {
        const int t = 2 * J;
        // ph1
        LDB4(0, 0, 0); LDA4(0, 0, 0, 0); STAGE(1, t + 1, 3);
        PHASE_TAIL(0, 0, 0);
        // ph2
        LDA4(0, 0, 1, 1); STAGE(0, t + 2, 0);
        PHASE_TAIL(1, 1, 0);
        // ph3
        LDB4(0, 1, 1); LDA4(0, 1, 0, 0); STAGE(0, t + 2, 1);
        PHASE_TAIL(0, 0, 1);
        // ph4
        LDA4(0, 1, 1, 1); STAGE(0, t + 2, 2);
        asm volatile("s_waitcnt vmcnt(6)" ::: "memory");
        PHASE_TAIL(1, 1, 1);
        // ph5
        LDB4(1, 0, 0); LDA4(1, 0, 0, 0); STAGE(0, t + 2, 3);
        PHASE_TAIL(0, 0, 0);
        // ph6
        LDA4(1, 0, 1, 1); STAGE(1, t + 3, 0);
        PHASE_TAIL(1, 1, 0);
        // ph7
        LDB4(1, 1, 1); LDA4(1, 1, 0, 0); STAGE(1, t + 3, 1);
        PHASE_TAIL(0, 0, 1);
        // ph8
        LDA4(1, 1, 1, 1); STAGE(1, t + 3, 2);
        asm volatile("s_waitcnt vmcnt(6)" ::: "memory");
        PHASE_TAIL(1, 1, 1);
    }

    // ---- final iteration (tiles NT-2, NT-1): drain ----
    {
        const int t = NT - 2;
        LDB4(0, 0, 0); LDA4(0, 0, 0, 0); STAGE(1, t + 1, 3);
        PHASE_TAIL(0, 0, 0);
        LDA4(0, 0, 1, 1);
        PHASE_TAIL(1, 1, 0);
        LDB4(0, 1, 1); LDA4(0, 1, 0, 0);
        PHASE_TAIL(0, 0, 1);
        LDA4(0, 1, 1, 1);
        asm volatile("s_waitcnt vmcnt(0)" ::: "memory");
        PHASE_TAIL(1, 1, 1);
        LDB4(1, 0, 0); LDA4(1, 0, 0, 0);
        PHASE_TAIL(0, 0, 0);
        LDA4(1, 0, 1, 1);
        PHASE_TAIL(1, 1, 0);
        LDB4(1, 1, 1); LDA4(1, 1, 0, 0);
        PHASE_TAIL(0, 0, 1);
        LDA4(1, 1, 1, 1);
        __builtin_amdgcn_s_barrier();
        asm volatile("s_waitcnt lgkmcnt(0)" ::: "memory");
        __builtin_amdgcn_s_setprio(1);
        MM4(1, 1, 1);
        __builtin_amdgcn_s_setprio(0);
    }

    // ---- epilogue ----
#pragma unroll
    for (int mt = 0; mt < 8; ++mt) {
#pragma unroll
        for (int nt = 0; nt < 4; ++nt) {
#pragma unroll
            for (int r = 0; r < 4; ++r) {
                const int m = m0 + wr * 128 + mt * 16 + quad * 4 + r;
                const int f = n0 + wc * 64 + nt * 16 + qcol;
                const float val = acc[mt][nt][r];
                if (MODE == 0) {
                    const int b     = m >> 9;          // T = 512
                    const int t     = m & 511;
                    const int which = f >> 11;
                    const int h     = (f >> 7) & 15;
                    const int d     = f & 127;
                    if (which == 2) {
                        o2[((size_t)(((b << 4) + h) * 128 + d) << 9) + t] = (bf16_t)val;
                    } else {
                        bf16_t* dst = (which == 0) ? o0 : o1;
                        dst[(size_t)(((b << 4) + h) * 512 + t) * 128 + d] = (bf16_t)val;
                    }
                } else {
                    of[(size_t)m * 2048 + f] = val;
                }
            }
        }
    }
}

// ---------------------------------------------------------------------------
// m97-structure GEMM (r0 harness-verified) — used for GEMM2 (M=4096, N=2048):
// 128x128 tile, BK=32, 4 waves, 16 KiB LDS -> ~3 blocks/CU, 512 blocks = full
// chip (vs gemm256's 128-block half-chip tail).  ~53 us at this shape in r0.
// MODE 1: fp32 store only.
// ---------------------------------------------------------------------------
template <int MODE>
__global__ __launch_bounds__(256)
void gemm_bt(const bf16_t* __restrict__ A, const bf16_t* __restrict__ Bm, int K,
             bf16_t* __restrict__ o0, bf16_t* __restrict__ o1, bf16_t* __restrict__ o2,
             float* __restrict__ of)
{
    __shared__ __align__(16) bf16_t As[128 * 32];
    __shared__ __align__(16) bf16_t Bs[128 * 32];
    const int tid  = threadIdx.x;
    const int lane = tid & 63;
    const int w    = tid >> 6;
    const int wm   = (w & 1) * 64;
    const int wn   = (w >> 1) * 64;
    const int m0   = blockIdx.x * 128;
    const int n0   = blockIdx.y * 128;
    const int quad = lane >> 4;
    const int qcol = lane & 15;

    f32x4 acc[4][4];
#pragma unroll
    for (int i = 0; i < 4; ++i)
#pragma unroll
        for (int j = 0; j < 4; ++j)
            acc[i][j] = (f32x4){0.f, 0.f, 0.f, 0.f};

    const int rc = lane >> 2;
    const int cg = (lane & 3) ^ (rc & 3);        // XOR-swizzled global col group
    const int c0 = 2 * w, c1 = 2 * w + 1;
    const bf16_t* ag0 = A  + (size_t)(m0 + 16 * c0 + rc) * K + cg * 8;
    const bf16_t* ag1 = A  + (size_t)(m0 + 16 * c1 + rc) * K + cg * 8;
    const bf16_t* bg0 = Bm + (size_t)(n0 + 16 * c0 + rc) * K + cg * 8;
    const bf16_t* bg1 = Bm + (size_t)(n0 + 16 * c1 + rc) * K + cg * 8;
    bf16_t* al0 = &As[c0 * 512];
    bf16_t* al1 = &As[c1 * 512];
    bf16_t* bl0 = &Bs[c0 * 512];
    bf16_t* bl1 = &Bs[c1 * 512];

    const int swz8 = (quad ^ (qcol & 3)) * 8;

    for (int k0 = 0; k0 < K; k0 += 32) {
        __syncthreads();
        __builtin_amdgcn_global_load_lds(GLB(ag0 + k0), LDS(al0), 16, 0, 0);
        __builtin_amdgcn_global_load_lds(GLB(ag1 + k0), LDS(al1), 16, 0, 0);
        __builtin_amdgcn_global_load_lds(GLB(bg0 + k0), LDS(bl0), 16, 0, 0);
        __builtin_amdgcn_global_load_lds(GLB(bg1 + k0), LDS(bl1), 16, 0, 0);
        __syncthreads();

        bf16x8 af[4], bf[4];
#pragma unroll
        for (int mt = 0; mt < 4; ++mt)
            af[mt] = *(const bf16x8*)&As[(wm + mt * 16 + qcol) * 32 + swz8];
#pragma unroll
        for (int nt = 0; nt < 4; ++nt)
            bf[nt] = *(const bf16x8*)&Bs[(wn + nt * 16 + qcol) * 32 + swz8];
#pragma unroll
        for (int mt = 0; mt < 4; ++mt)
#pragma unroll
            for (int nt = 0; nt < 4; ++nt)
                acc[mt][nt] = __builtin_amdgcn_mfma_f32_16x16x32_bf16(af[mt], bf[nt], acc[mt][nt], 0, 0, 0);
    }

#pragma unroll
    for (int mt = 0; mt < 4; ++mt) {
#pragma unroll
        for (int nt = 0; nt < 4; ++nt) {
#pragma unroll
            for (int r = 0; r < 4; ++r) {
                const int m = m0 + wm + mt * 16 + quad * 4 + r;
                const int f = n0 + wn + nt * 16 + qcol;
                const float val = acc[mt][nt][r];
                of[(size_t)m * 2048 + f] = val;
            }
        }
    }
}

// ---------------------------------------------------------------------------
// RoPE (in-place on bf16 q and k; v untouched)
// ---------------------------------------------------------------------------
__global__ void rope_kernel(bf16_t* __restrict__ q, bf16_t* __restrict__ k)
{
    const int id  = blockIdx.x * 256 + threadIdx.x;
    const int arr = id >> 19;
    const int rem = id & ((1 << 19) - 1);
    const int bh  = rem >> 12;
    const int t   = (rem >> 3) & 511;
    const int d   = rem & 7;

    bf16_t* p = (arr ? k : q) + (size_t)(bh * 512 + t) * 128;
    const float x1 = (float)p[d];
    const float x2 = (float)p[d + 8];
    const float freq = __expf(-(float)d * 1.1512925464970229f);  // ln(10000)/8
    const float ang  = (float)t * freq;
    const float c = cosf(ang), s = sinf(ang);
    p[d]     = (bf16_t)(x1 * c - x2 * s);
    p[d + 8] = (bf16_t)(x2 * c + x1 * s);
}

// ---------------------------------------------------------------------------
// MFMA flash attention, BQ=256, BK=64.  Block = 512 thr (8 waves = 2/SIMD)
// per (b, h, 256-query tile); grid 2x16x8 = 256 blocks.  Wave w owns 32
// queries (2 x 16-query groups qg).  K/V staged once per 256 queries; 2
// waves/SIMD hide the serial QK->softmax->P->PV chain.  Per-wave skip of
// fully-masked K-tiles.  S^T = K·Q^T; shfl softmax; P via wave-private LDS;
// O += P·V with V^T staged from (B,H,hd,T).
// ---------------------------------------------------------------------------
#define KLD 136
#define VLD 72
#define PLD 72

__global__ __launch_bounds__(512)
void flash_attn(const bf16_t* __restrict__ q, const bf16_t* __restrict__ k,
                const bf16_t* __restrict__ vT, bf16_t* __restrict__ y)
{
    const int qtb = blockIdx.x;   // 0..1 (256-query tiles)
    const int h   = blockIdx.y;
    const int b   = blockIdx.z;
    const int tid  = threadIdx.x;
    const int lane = tid & 63;
    const int w    = tid >> 6;    // 0..7
    const int quad = lane >> 4;
    const int qcol = lane & 15;

    __shared__ __align__(16) bf16_t Ks[64 * KLD];      // keys x dims   (17.4 KB)
    __shared__ __align__(16) bf16_t VTs[128 * VLD];    // dims x keys   (18.4 KB)
    __shared__ __align__(16) bf16_t Ps[256 * PLD];     // queries x keys(36.9 KB)
    __shared__ __align__(16) float aS[8][2][16];
    __shared__ __align__(16) float lS[8][2][16];

    const bf16_t* qb  = q  + (size_t)((b * 16 + h) * 512) * 128;
    const bf16_t* kb  = k  + (size_t)((b * 16 + h) * 512) * 128;
    const bf16_t* vtb = vT + (size_t)((b * 16 + h) * 128) * 512;

    // Q fragments (B-operand): query = qtb*256 + w*32 + qg*16 + qcol
    bf16x8 qfrag[2][4];
#pragma unroll
    for (int qg = 0; qg < 2; ++qg) {
        const int qrow = qtb * 256 + w * 32 + qg * 16 + qcol;
#pragma unroll
        for (int kc = 0; kc < 4; ++kc)
            qfrag[qg][kc] = *(const bf16x8*)&qb[(size_t)qrow * 128 + kc * 32 + quad * 8];
    }

    f32x4 acc_o[2][8];
#pragma unroll
    for (int qg = 0; qg < 2; ++qg)
#pragma unroll
        for (int nt = 0; nt < 8; ++nt) acc_o[qg][nt] = (f32x4){0.f, 0.f, 0.f, 0.f};
    float m_run[2] = {-INFINITY, -INFINITY};
    float l_run[2] = {0.f, 0.f};
    const float scale = 0.08838834764831845f;   // 1/sqrt(128)

    const int wq_min  = qtb * 256 + w * 32;     // wave's lowest query
    const int kt_last = 4 * qtb + 3;
    for (int kt = 0; kt <= kt_last; ++kt) {
        __syncthreads();
        // stage K tile (64 keys x 128 dims): 512 thr x 2 x 16B
#pragma unroll
        for (int p = 0; p < 2; ++p) {
            const int r = p * 32 + (tid >> 4), c = (tid & 15) * 8;
            *(uint4*)&Ks[r * KLD + c] = *(const uint4*)&kb[(size_t)(kt * 64 + r) * 128 + c];
        }
        // stage V^T tile (128 dims x 64 keys): 512 thr x 2 x 16B
#pragma unroll
        for (int p = 0; p < 2; ++p) {
            const int r = p * 64 + (tid >> 3), c = (tid & 7) * 8;
            *(uint4*)&VTs[r * VLD + c] = *(const uint4*)&vtb[(size_t)r * 512 + kt * 64 + c];
        }
        __syncthreads();

        // per-wave: skip fully-masked tiles (all keys > all of wave's queries)
        if (kt * 64 > wq_min + 31) continue;
        const bool need_mask = ((kt + 1) * 64 > wq_min);

#pragma unroll
        for (int qg = 0; qg < 2; ++qg) {
            // S^T (M=64 keys, N=16 queries, K=128): 16 MFMA
            f32x4 sacc[4];
#pragma unroll
            for (int mt = 0; mt < 4; ++mt) sacc[mt] = (f32x4){0.f, 0.f, 0.f, 0.f};
#pragma unroll
            for (int mt = 0; mt < 4; ++mt)
#pragma unroll
                for (int kc = 0; kc < 4; ++kc) {
                    bf16x8 af = *(const bf16x8*)&Ks[(mt * 16 + qcol) * KLD + kc * 32 + quad * 8];
                    sacc[mt] = __builtin_amdgcn_mfma_f32_16x16x32_bf16(af, qfrag[qg][kc], sacc[mt], 0, 0, 0);
                }

            float s[16];
#pragma unroll
            for (int mt = 0; mt < 4; ++mt)
#pragma unroll
                for (int r = 0; r < 4; ++r)
                    s[mt * 4 + r] = sacc[mt][r] * scale;
            if (need_mask) {
                const int qglob = qtb * 256 + w * 32 + qg * 16 + qcol;
#pragma unroll
                for (int mt = 0; mt < 4; ++mt)
#pragma unroll
                    for (int r = 0; r < 4; ++r)
                        if (kt * 64 + mt * 16 + quad * 4 + r > qglob)
                            s[mt * 4 + r] = -1e30f;
            }

            float mx = s[0];
#pragma unroll
            for (int i = 1; i < 16; ++i) mx = fmaxf(mx, s[i]);
            mx = fmaxf(mx, __shfl_xor(mx, 16));
            mx = fmaxf(mx, __shfl_xor(mx, 32));
            const float m_new = fmaxf(m_run[qg], mx);
            const float alpha = __expf(m_run[qg] - m_new);   // first iter: exp(-inf)=0
            float p16[16];
            float sum = 0.f;
#pragma unroll
            for (int i = 0; i < 16; ++i) { p16[i] = __expf(s[i] - m_new); sum += p16[i]; }
            sum += __shfl_xor(sum, 16);
            sum += __shfl_xor(sum, 32);
            l_run[qg] = l_run[qg] * alpha + sum;
            m_run[qg] = m_new;
            if (quad == 0) aS[w][qg][qcol] = alpha;

            // P -> wave-private LDS rows [w*32 + qg*16, +16)
#pragma unroll
            for (int mt = 0; mt < 4; ++mt) {
                bf16x4 pb = {(bf16_t)p16[mt * 4 + 0], (bf16_t)p16[mt * 4 + 1],
                             (bf16_t)p16[mt * 4 + 2], (bf16_t)p16[mt * 4 + 3]};
                *(bf16x4*)&Ps[(w * 32 + qg * 16 + qcol) * PLD + mt * 16 + quad * 4] = pb;
            }

            // rescale O rows (query = quad*4 + r within qg) by alpha
            f32x4 alpha4 = *(const f32x4*)&aS[w][qg][quad * 4];
#pragma unroll
            for (int nt = 0; nt < 8; ++nt)
#pragma unroll
                for (int r = 0; r < 4; ++r)
                    acc_o[qg][nt][r] *= alpha4[r];

            // O += P·V (M=16 queries, N=128 dims, K=64 keys): 16 MFMA
#pragma unroll
            for (int kc2 = 0; kc2 < 2; ++kc2) {
                bf16x8 pf = *(const bf16x8*)&Ps[(w * 32 + qg * 16 + qcol) * PLD + kc2 * 32 + quad * 8];
#pragma unroll
                for (int nt = 0; nt < 8; ++nt) {
                    bf16x8 vf = *(const bf16x8*)&VTs[(nt * 16 + qcol) * VLD + kc2 * 32 + quad * 8];
                    acc_o[qg][nt] = __builtin_amdgcn_mfma_f32_16x16x32_bf16(pf, vf, acc_o[qg][nt], 0, 0, 0);
                }
            }
        }
    }

    // epilogue: y[(b, t, h*128 + d)] = O / l
    if (quad == 0) { lS[w][0][qcol] = l_run[0]; lS[w][1][qcol] = l_run[1]; }
#pragma unroll
    for (int qg = 0; qg < 2; ++qg) {
        f32x4 l4 = *(const f32x4*)&lS[w][qg][quad * 4];
#pragma unroll
        for (int nt = 0; nt < 8; ++nt)
#pragma unroll
            for (int r = 0; r < 4; ++r) {
                const int t  = qtb * 256 + w * 32 + qg * 16 + quad * 4 + r;
                const int cc = h * 128 + nt * 16 + qcol;
                y[(size_t)(b * 512 + t) * 2048 + cc] = (bf16_t)(acc_o[qg][nt][r] / l4[r]);
            }
    }
}

// ---------------------------------------------------------------------------
extern "C" void kernel_launch(void* const* d_in, const int* in_sizes, int n_in,
                              void* d_out, int out_size, void* d_ws, size_t ws_size,
                              hipStream_t stream)
{
    (void)in_sizes; (void)n_in; (void)out_size; (void)ws_size;

    const float* x    = (const float*)d_in[0];   // (8, 512, 2048) fp32
    const float* Wqkv = (const float*)d_in[1];   // (6144, 2048)  fp32
    const float* Wout = (const float*)d_in[2];   // (2048, 2048)  fp32
    float* out = (float*)d_out;                  // (8, 512, 2048) fp32

    const size_t SEG = (size_t)8 * 16 * 512 * 128;   // 8,388,608 elems (16 MB bf16)
    bf16_t* q      = (bf16_t*)d_ws;          // [0, 16 MB)
    bf16_t* k      = q + SEG;                // [16, 32)
    bf16_t* vT     = k + SEG;                // [32, 48)   (B,H,hd,T)
    bf16_t* xb     = vT + SEG;               // [48, 64)   bf16 x — dead after GEMM1
    bf16_t* y      = xb;                     //            y aliases xb
    bf16_t* Wqkvb  = xb + SEG;               // [64, 88)   bf16 Wqkv
    bf16_t* Woutb  = Wqkvb + (size_t)6144 * 2048;   // [88, 96)

    f32_to_bf16<<<(8388608 / 8) / 256, 256, 0, stream>>>(x, xb, 8388608 / 8);
    f32_to_bf16<<<(12582912 / 8) / 256, 256, 0, stream>>>(Wqkv, Wqkvb, 12582912 / 8);
    f32_to_bf16<<<(4194304 / 8) / 256, 256, 0, stream>>>(Wout, Woutb, 4194304 / 8);
    gemm256<0><<<dim3(4096 / 256, 6144 / 256), 512, 0, stream>>>(xb, Wqkvb, 2048, q, k, vT, nullptr);
    rope_kernel<<<(2 * 128 * 512 * 8) / 256, 256, 0, stream>>>(q, k);
    flash_attn<<<dim3(2, 16, 8), 512, 0, stream>>>(q, k, vT, y);
    gemm_bt<1><<<dim3(4096 / 128, 2048 / 128), 256, 0, stream>>>(y, Woutb, 2048, nullptr, nullptr, nullptr, out);
}